// Round 2
// baseline (516.316 us; speedup 1.0000x reference)
//
#include <hip/hip_runtime.h>

// Problem constants (from setup_inputs): x (8,128,256,256) f32, mask (8,1,256,256) f32 (0/1)
constexpr int Bn = 8, Cn = 128;
constexpr int HW = 256 * 256;          // 65536 per (b,c) plane
constexpr int HW4 = HW / 4;            // 16384 float4 per plane  (== 1<<14)
constexpr int NPC = Bn * HW;           // 524288 elements per channel
constexpr int TOT = Bn * Cn * HW;      // 67108864 total elements
constexpr int CHUNKS = 8;              // reduce blocks per channel (== Bn here)
constexpr int RBLK = 256;
constexpr float EPSf = 1e-5f;

__device__ __forceinline__ float wave_reduce(float v) {
#pragma unroll
    for (int off = 32; off > 0; off >>= 1) v += __shfl_xor(v, off, 64);
    return v;
}

// Pass 1: per-channel sums of {x, x^2, x*m, x^2*m} + global sum(mask).
// sums layout: sums[c*4 + {0..3}] = {s_all, ss_all, s_fg, ss_fg}; sums[4*Cn] = Sr.
__global__ __launch_bounds__(RBLK) void rn_reduce(const float* __restrict__ x,
                                                  const float* __restrict__ mask,
                                                  float* __restrict__ sums) {
    const int c = blockIdx.x / CHUNKS;
    const int chunk = blockIdx.x % CHUNKS;
    const int vpb = (NPC / 4) / CHUNKS;  // 16384 float4 per block
    const int base = chunk * vpb;

    const float4* x4 = reinterpret_cast<const float4*>(x);
    const float4* m4 = reinterpret_cast<const float4*>(mask);

    float s_a = 0.f, ss_a = 0.f, s_f = 0.f, ss_f = 0.f, sm = 0.f;
    for (int i = base + (int)threadIdx.x; i < base + vpb; i += RBLK) {
        const int b   = i >> 14;         // i / HW4
        const int hw4 = i & (HW4 - 1);
        const float4 xv = x4[((size_t)(b * Cn + c) << 14) + hw4];
        const float4 mv = m4[((size_t)b << 14) + hw4];
        s_a  += (xv.x + xv.y) + (xv.z + xv.w);
        ss_a += fmaf(xv.x, xv.x, fmaf(xv.y, xv.y, fmaf(xv.z, xv.z, xv.w * xv.w)));
        s_f  += fmaf(xv.x, mv.x, fmaf(xv.y, mv.y, fmaf(xv.z, mv.z, xv.w * mv.w)));
        ss_f += fmaf(xv.x * xv.x, mv.x, fmaf(xv.y * xv.y, mv.y,
                 fmaf(xv.z * xv.z, mv.z, (xv.w * xv.w) * mv.w)));
        sm   += (mv.x + mv.y) + (mv.z + mv.w);
    }

    s_a = wave_reduce(s_a);
    ss_a = wave_reduce(ss_a);
    s_f = wave_reduce(s_f);
    ss_f = wave_reduce(ss_f);
    sm = wave_reduce(sm);

    __shared__ float red[4][5];
    const int wave = threadIdx.x >> 6, lane = threadIdx.x & 63;
    if (lane == 0) {
        red[wave][0] = s_a; red[wave][1] = ss_a; red[wave][2] = s_f;
        red[wave][3] = ss_f; red[wave][4] = sm;
    }
    __syncthreads();
    if (threadIdx.x == 0) {
        float t0 = 0.f, t1 = 0.f, t2 = 0.f, t3 = 0.f, t4 = 0.f;
#pragma unroll
        for (int w = 0; w < 4; ++w) {
            t0 += red[w][0]; t1 += red[w][1]; t2 += red[w][2];
            t3 += red[w][3]; t4 += red[w][4];
        }
        atomicAdd(&sums[c * 4 + 0], t0);
        atomicAdd(&sums[c * 4 + 1], t1);
        atomicAdd(&sums[c * 4 + 2], t2);
        atomicAdd(&sums[c * 4 + 3], t3);
        if (c == 0) atomicAdd(&sums[4 * Cn], t4);  // mask covered exactly once by c==0 blocks
    }
}

// Pass 2 (tiny): fold stats + gamma/beta into per-channel linear coefficients.
// out = mask ? x*A1 + D1 : x*A0 + D0   -> coef[c] = (A1, D1, A0, D0)
__global__ void rn_finalize(const float* __restrict__ sums,
                            const float* __restrict__ fg_gamma, const float* __restrict__ fg_beta,
                            const float* __restrict__ bg_gamma, const float* __restrict__ bg_beta,
                            float4* __restrict__ coef) {
    const int c = threadIdx.x;
    if (c >= Cn) return;
    const float Nf = (float)NPC;
    const float Sr = sums[4 * Cn];
    const float Srf = (Sr == 0.f) ? 1.f : Sr;       // jnp.where(Sr==0, 1, Sr)
    const float Srb = Nf - Sr;
    const float Srbf = (Srb == 0.f) ? 1.f : Srb;

    const float s_a = sums[c * 4 + 0], ss_a = sums[c * 4 + 1];
    const float s_f = sums[c * 4 + 2], ss_f = sums[c * 4 + 3];
    const float s_b = s_a - s_f, ss_b = ss_a - ss_f;

    // fg stats: y = x on region, mu_f elsewhere
    const float mu_f   = s_f / Srf;
    const float mean_f = (s_f + (Nf - Sr) * mu_f) / Nf;
    const float Ey2_f  = (ss_f + (Nf - Sr) * mu_f * mu_f) / Nf;
    const float var_f  = Ey2_f - mean_f * mean_f;
    const float G_f    = rsqrtf(var_f + EPSf) * sqrtf(Srf / Nf);

    // bg stats
    const float mu_b   = s_b / Srbf;
    const float mean_b = (s_b + (Nf - Srb) * mu_b) / Nf;
    const float Ey2_b  = (ss_b + (Nf - Srb) * mu_b * mu_b) / Nf;
    const float var_b  = Ey2_b - mean_b * mean_b;
    const float G_b    = rsqrtf(var_b + EPSf) * sqrtf(Srbf / Nf);

    const float Bsum = fg_beta[c] + bg_beta[c];
    const float gf = 1.f + fg_gamma[c];
    const float gb = 1.f + bg_gamma[c];
    // cross-region constants (exactly 0 when mean==mu, kept for bit-faithfulness)
    const float cIn1 = (mu_b - mean_b) * G_b;   // bg's bn value at mask==1 pixels
    const float cIn0 = (mu_f - mean_f) * G_f;   // fg's bn value at mask==0 pixels

    const float A1 = G_f * gf;
    const float D1 = (cIn1 - mean_f * G_f) * gf + Bsum;
    const float A0 = G_b * gb;
    const float D0 = (cIn0 - mean_b * G_b) * gb + Bsum;
    coef[c] = make_float4(A1, D1, A0, D0);
}

// Pass 3: streaming apply, float4.
__global__ __launch_bounds__(256) void rn_apply(const float* __restrict__ x,
                                                const float* __restrict__ mask,
                                                const float4* __restrict__ coef,
                                                float* __restrict__ out) {
    const int total4 = TOT / 4;
    const float4* x4 = reinterpret_cast<const float4*>(x);
    const float4* m4 = reinterpret_cast<const float4*>(mask);
    float4* o4 = reinterpret_cast<float4*>(out);
    const int stride = gridDim.x * blockDim.x;
    for (int i = blockIdx.x * blockDim.x + threadIdx.x; i < total4; i += stride) {
        const int hw4 = i & (HW4 - 1);
        const int bc  = i >> 14;
        const int c   = bc & (Cn - 1);
        const int b   = bc >> 7;
        const float4 xv = x4[i];
        const float4 mv = m4[((size_t)b << 14) + hw4];
        const float4 k = coef[c];
        float4 ov;
        ov.x = fmaf(xv.x, mv.x > 0.5f ? k.x : k.z, mv.x > 0.5f ? k.y : k.w);
        ov.y = fmaf(xv.y, mv.y > 0.5f ? k.x : k.z, mv.y > 0.5f ? k.y : k.w);
        ov.z = fmaf(xv.z, mv.z > 0.5f ? k.x : k.z, mv.z > 0.5f ? k.y : k.w);
        ov.w = fmaf(xv.w, mv.w > 0.5f ? k.x : k.z, mv.w > 0.5f ? k.y : k.w);
        o4[i] = ov;
    }
}

extern "C" void kernel_launch(void* const* d_in, const int* in_sizes, int n_in,
                              void* d_out, int out_size, void* d_ws, size_t ws_size,
                              hipStream_t stream) {
    const float* x        = (const float*)d_in[0];
    const float* mask     = (const float*)d_in[1];
    const float* fg_gamma = (const float*)d_in[2];
    const float* fg_beta  = (const float*)d_in[3];
    const float* bg_gamma = (const float*)d_in[4];
    const float* bg_beta  = (const float*)d_in[5];
    float* out = (float*)d_out;

    float*  sums = (float*)d_ws;                       // 4*Cn+1 floats (poisoned -> zero it)
    float4* coef = (float4*)((char*)d_ws + 4096);      // 128 float4, fully overwritten

    hipMemsetAsync(sums, 0, (4 * Cn + 1) * sizeof(float), stream);
    rn_reduce<<<Cn * CHUNKS, RBLK, 0, stream>>>(x, mask, sums);
    rn_finalize<<<1, 128, 0, stream>>>(sums, fg_gamma, fg_beta, bg_gamma, bg_beta, coef);
    rn_apply<<<2048, 256, 0, stream>>>(x, mask, coef, out);
}

// Round 5
// 505.589 us; speedup vs baseline: 1.0212x; 1.0212x over previous
//
#include <hip/hip_runtime.h>

// x (8,128,256,256) f32, mask (8,1,256,256) f32 in {0,1}
constexpr int Bn = 8, Cn = 128;
constexpr int HW = 256 * 256;          // elements per plane
constexpr int HW4 = HW / 4;            // 16384 float4 per plane (1<<14)
constexpr int NPC = Bn * HW;           // 524288 elements per channel
constexpr int CHUNKS = 16;             // reduce blocks per channel (half-plane each)
constexpr int VPB = (NPC / 4) / CHUNKS;  // 8192 float4 per reduce block
constexpr float EPSf = 1e-5f;

typedef float floatx4 __attribute__((ext_vector_type(4)));  // nontemporal-store-legal

__device__ __forceinline__ float wave_reduce(float v) {
#pragma unroll
    for (int off = 32; off > 0; off >>= 1) v += __shfl_xor(v, off, 64);
    return v;
}

// Pass 1: per-(channel,chunk) partial sums of {x, x^2, x*m, x^2*m}; c==0 blocks
// also write partial sum(mask). No atomics, no memset: partials fully overwritten.
__global__ __launch_bounds__(256) void rn_reduce(const float* __restrict__ x,
                                                 const float* __restrict__ mask,
                                                 float4* __restrict__ part,
                                                 float* __restrict__ partm) {
    const int c = blockIdx.x >> 4;        // /CHUNKS
    const int chunk = blockIdx.x & (CHUNKS - 1);
    const int base = chunk * VPB;         // float4 index within this channel's NPC/4 space

    const float4* x4 = reinterpret_cast<const float4*>(x);
    const float4* m4 = reinterpret_cast<const float4*>(mask);

    float s_a = 0.f, ss_a = 0.f, s_f = 0.f, ss_f = 0.f, sm = 0.f;
    for (int i = base + (int)threadIdx.x; i < base + VPB; i += 256) {
        const int b   = i >> 14;          // i / HW4
        const int hw4 = i & (HW4 - 1);
        const float4 xv = x4[((size_t)(b * Cn + c) << 14) + hw4];
        const float4 mv = m4[((size_t)b << 14) + hw4];
        s_a  += (xv.x + xv.y) + (xv.z + xv.w);
        ss_a += fmaf(xv.x, xv.x, fmaf(xv.y, xv.y, fmaf(xv.z, xv.z, xv.w * xv.w)));
        s_f  += fmaf(xv.x, mv.x, fmaf(xv.y, mv.y, fmaf(xv.z, mv.z, xv.w * mv.w)));
        ss_f += fmaf(xv.x * xv.x, mv.x, fmaf(xv.y * xv.y, mv.y,
                 fmaf(xv.z * xv.z, mv.z, (xv.w * xv.w) * mv.w)));
        sm   += (mv.x + mv.y) + (mv.z + mv.w);
    }

    s_a = wave_reduce(s_a); ss_a = wave_reduce(ss_a);
    s_f = wave_reduce(s_f); ss_f = wave_reduce(ss_f);
    sm  = wave_reduce(sm);

    __shared__ float red[4][5];
    const int wave = threadIdx.x >> 6, lane = threadIdx.x & 63;
    if (lane == 0) {
        red[wave][0] = s_a; red[wave][1] = ss_a; red[wave][2] = s_f;
        red[wave][3] = ss_f; red[wave][4] = sm;
    }
    __syncthreads();
    if (threadIdx.x == 0) {
        float t0 = 0.f, t1 = 0.f, t2 = 0.f, t3 = 0.f, t4 = 0.f;
#pragma unroll
        for (int w = 0; w < 4; ++w) {
            t0 += red[w][0]; t1 += red[w][1]; t2 += red[w][2];
            t3 += red[w][3]; t4 += red[w][4];
        }
        part[blockIdx.x] = make_float4(t0, t1, t2, t3);
        if (c == 0) partm[chunk] = t4;   // mask covered exactly once by c==0 blocks
    }
}

// Pass 2 (tiny): fold partials + gamma/beta into per-channel linear coefficients.
// out = mask ? x*A1 + D1 : x*A0 + D0   -> coef[c] = (A1, D1, A0, D0)
__global__ void rn_finalize(const float4* __restrict__ part, const float* __restrict__ partm,
                            const float* __restrict__ fg_gamma, const float* __restrict__ fg_beta,
                            const float* __restrict__ bg_gamma, const float* __restrict__ bg_beta,
                            float4* __restrict__ coef) {
    const int c = threadIdx.x;
    if (c >= Cn) return;
    float Sr = 0.f;
#pragma unroll
    for (int k = 0; k < CHUNKS; ++k) Sr += partm[k];
    float s_a = 0.f, ss_a = 0.f, s_f = 0.f, ss_f = 0.f;
#pragma unroll
    for (int k = 0; k < CHUNKS; ++k) {
        const float4 p = part[c * CHUNKS + k];
        s_a += p.x; ss_a += p.y; s_f += p.z; ss_f += p.w;
    }
    const float Nf = (float)NPC;
    const float Srf = (Sr == 0.f) ? 1.f : Sr;        // jnp.where(Sr==0, 1, Sr)
    const float Srb = Nf - Sr;
    const float Srbf = (Srb == 0.f) ? 1.f : Srb;
    const float s_b = s_a - s_f, ss_b = ss_a - ss_f;

    // fg stats: y = x on region, mu_f elsewhere
    const float mu_f   = s_f / Srf;
    const float mean_f = (s_f + (Nf - Sr) * mu_f) / Nf;
    const float Ey2_f  = (ss_f + (Nf - Sr) * mu_f * mu_f) / Nf;
    const float var_f  = Ey2_f - mean_f * mean_f;
    const float G_f    = rsqrtf(var_f + EPSf) * sqrtf(Srf / Nf);
    // bg stats
    const float mu_b   = s_b / Srbf;
    const float mean_b = (s_b + (Nf - Srb) * mu_b) / Nf;
    const float Ey2_b  = (ss_b + (Nf - Srb) * mu_b * mu_b) / Nf;
    const float var_b  = Ey2_b - mean_b * mean_b;
    const float G_b    = rsqrtf(var_b + EPSf) * sqrtf(Srbf / Nf);

    const float Bsum = fg_beta[c] + bg_beta[c];
    const float gf = 1.f + fg_gamma[c];
    const float gb = 1.f + bg_gamma[c];
    const float cIn1 = (mu_b - mean_b) * G_b;   // bg bn value at mask==1 pixels (≈0, kept exact)
    const float cIn0 = (mu_f - mean_f) * G_f;   // fg bn value at mask==0 pixels

    const float A1 = G_f * gf;
    const float D1 = (cIn1 - mean_f * G_f) * gf + Bsum;
    const float A0 = G_b * gb;
    const float D0 = (cIn0 - mean_b * G_b) * gb + Bsum;
    coef[c] = make_float4(A1, D1, A0, D0);
}

// Pass 3: streaming apply. One half-plane per block -> block-uniform coef.
// Non-temporal stores keep x resident in L3 (x == 256 MiB == L3 size) so the
// re-read of x hits Infinity Cache instead of HBM.
__global__ __launch_bounds__(256) void rn_apply(const float* __restrict__ x,
                                                const float* __restrict__ mask,
                                                const float4* __restrict__ coef,
                                                float* __restrict__ out) {
    const int plane = blockIdx.x >> 1;            // b*Cn + c
    const int c = plane & (Cn - 1);
    const int b = plane >> 7;
    const size_t base  = ((size_t)plane << 14) + ((size_t)(blockIdx.x & 1) << 13);
    const size_t mbase = ((size_t)b << 14) + ((size_t)(blockIdx.x & 1) << 13);

    const float4* x4 = reinterpret_cast<const float4*>(x);
    const float4* m4 = reinterpret_cast<const float4*>(mask);
    floatx4* o4 = reinterpret_cast<floatx4*>(out);
    const float4 k = coef[c];

    for (int t = threadIdx.x; t < (HW4 / 2); t += 256) {
        const float4 xv = x4[base + t];
        const float4 mv = m4[mbase + t];
        floatx4 ov;
        ov.x = fmaf(xv.x, mv.x > 0.5f ? k.x : k.z, mv.x > 0.5f ? k.y : k.w);
        ov.y = fmaf(xv.y, mv.y > 0.5f ? k.x : k.z, mv.y > 0.5f ? k.y : k.w);
        ov.z = fmaf(xv.z, mv.z > 0.5f ? k.x : k.z, mv.z > 0.5f ? k.y : k.w);
        ov.w = fmaf(xv.w, mv.w > 0.5f ? k.x : k.z, mv.w > 0.5f ? k.y : k.w);
        __builtin_nontemporal_store(ov, &o4[base + t]);
    }
}

extern "C" void kernel_launch(void* const* d_in, const int* in_sizes, int n_in,
                              void* d_out, int out_size, void* d_ws, size_t ws_size,
                              hipStream_t stream) {
    const float* x        = (const float*)d_in[0];
    const float* mask     = (const float*)d_in[1];
    const float* fg_gamma = (const float*)d_in[2];
    const float* fg_beta  = (const float*)d_in[3];
    const float* bg_gamma = (const float*)d_in[4];
    const float* bg_beta  = (const float*)d_in[5];
    float* out = (float*)d_out;

    // d_ws layout (all regions fully overwritten each call; poison-safe):
    float4* part  = (float4*)d_ws;                         // 2048 float4 = 32 KiB
    float*  partm = (float*)((char*)d_ws + 32768);         // 16 floats
    float4* coef  = (float4*)((char*)d_ws + 36864);        // 128 float4

    rn_reduce<<<Cn * CHUNKS, 256, 0, stream>>>(x, mask, part, partm);
    rn_finalize<<<1, 128, 0, stream>>>(part, partm, fg_gamma, fg_beta,
                                       bg_gamma, bg_beta, coef);
    rn_apply<<<Bn * Cn * 2, 256, 0, stream>>>(x, mask, coef, out);
}